// Round 14
// baseline (664.383 us; speedup 1.0000x reference)
//
#include <hip/hip_runtime.h>
#include <stdint.h>

#define DIMD 4096   // feature width (and K)
#define DIMB 4096   // batch
#define NLAYER 4
#define NT (DIMD / 64)   // 64 K-tiles of BK=64

typedef unsigned short u16;
typedef __attribute__((ext_vector_type(8))) unsigned short us8;
typedef __attribute__((ext_vector_type(4))) float f32x4;
typedef __attribute__((ext_vector_type(8))) __bf16 bf16x8;

__device__ __forceinline__ u16 f2bf(float f) {
    union { float f; uint32_t u; } v; v.f = f;
    return (u16)((v.u + 0x7fffu + ((v.u >> 16) & 1u)) >> 16);  // RNE
}
__device__ __forceinline__ float bf2f(u16 u) {
    union { uint32_t u; float f; } v; v.u = ((uint32_t)u) << 16;
    return v.f;
}

// ---------------- fp32 -> bf16 elementwise (x input) ----------------
__global__ void k_cvt(const float* __restrict__ in, u16* __restrict__ out) {
    int i = (blockIdx.x * 256 + threadIdx.x) * 4;
    float4 v = *reinterpret_cast<const float4*>(in + i);
    ushort4 r;
    r.x = f2bf(v.x); r.y = f2bf(v.y); r.z = f2bf(v.z); r.w = f2bf(v.w);
    *reinterpret_cast<ushort4*>(out + i) = r;
}

// ------- W[k][n] fp32 -> Wt[n][k] bf16 (layer 0 only; layers 1-3 are
//         transposed inside the GEMMs, hidden under the K-loop) -------
__global__ void k_trans(const float* __restrict__ W, u16* __restrict__ Wt) {
    __shared__ float tile[64][65];
    const int t = threadIdx.x;
    const int n0 = blockIdx.x * 64, k0 = blockIdx.y * 64;
    const int kr = t >> 4, c4 = (t & 15) * 4;
    #pragma unroll
    for (int r = 0; r < 4; ++r) {
        float4 v = *reinterpret_cast<const float4*>(W + (size_t)(k0 + kr + r * 16) * DIMD + n0 + c4);
        tile[kr + r * 16][c4 + 0] = v.x;
        tile[kr + r * 16][c4 + 1] = v.y;
        tile[kr + r * 16][c4 + 2] = v.z;
        tile[kr + r * 16][c4 + 3] = v.w;
    }
    __syncthreads();
    const int nr = t >> 4, k4 = (t & 15) * 4;
    #pragma unroll
    for (int r = 0; r < 4; ++r) {
        int n = nr + r * 16;
        ushort4 o;
        o.x = f2bf(tile[k4 + 0][n]);
        o.y = f2bf(tile[k4 + 1][n]);
        o.z = f2bf(tile[k4 + 2][n]);
        o.w = f2bf(tile[k4 + 3][n]);
        *reinterpret_cast<ushort4*>(Wt + (size_t)(n0 + n) * DIMD + k0 + k4) = o;
    }
}

// ------- 256x256 8-phase bf16 MFMA GEMM — r3 schedule, x2 unroll -------
// + r12 LDS-transpose epilogue (16B vector C-stores)
// + r13 next-layer weight-transpose side-channel (hidden under K-loop)
// + r14: template's optional lgkmcnt(8) throttle at P1 (12 reads issued)
#define GLD(g, l) __builtin_amdgcn_global_load_lds( \
    (__attribute__((address_space(1))) void*)(g),   \
    (__attribute__((address_space(3))) void*)(l), 16, 0, 0)

#define VMW8 asm volatile("s_waitcnt vmcnt(8)" ::: "memory")
#define VMW0 asm volatile("s_waitcnt vmcnt(0)" ::: "memory")
#define LGKM0 asm volatile("s_waitcnt lgkmcnt(0)" ::: "memory")
#define LGKM8 asm volatile("s_waitcnt lgkmcnt(8)" ::: "memory")

__global__ __launch_bounds__(512, 2) void k_gemm(
        const u16* __restrict__ A, const u16* __restrict__ Bt,
        const float* __restrict__ bias, u16* __restrict__ H,
        float* __restrict__ Hf,
        float* __restrict__ csum, float* __restrict__ csum2,
        const float* __restrict__ Wn, u16* __restrict__ WtN) {
    __shared__ __attribute__((aligned(16))) u16 As[2 * 256 * 64];   // 64 KiB
    __shared__ __attribute__((aligned(16))) u16 Bs[2 * 256 * 64];   // 64 KiB
    const int tid = threadIdx.x;
    const int lane = tid & 63, wv = tid >> 6;
    const int wm = wv >> 2, wn = wv & 3;          // 2 x 4 wave grid
    const int bm = blockIdx.y, bn = blockIdx.x;
    const int bid = bm * 16 + bn;                 // 0..255 for W side-channel
    const int lr = lane & 15, lk = lane >> 4;

    // staging geometry: per GLD issue, 512 threads x 16B cover 64 rows x 64 cols
    const int r0 = tid >> 3;                       // 0..63
    const int cswz = (tid & 7) ^ (r0 & 7);         // inverse-swizzled 16B chunk
    const u16* gA = A  + (size_t)(bm * 256 + r0) * DIMD + cswz * 8;
    const u16* gB = Bt + (size_t)(bn * 256 + r0) * DIMD + cswz * 8;

#define STAGE_A(h, t, buf) do { \
    const u16* _s = gA + (size_t)(h) * 128 * DIMD + (size_t)(t) * 64; \
    u16* _d = As + (buf) * 16384 + (h) * 8192 + wv * 512; \
    GLD(_s, _d); GLD(_s + (size_t)64 * DIMD, _d + 4096); \
} while (0)
#define STAGE_B(h, t, buf) do { \
    const u16* _s = gB + (size_t)(h) * 128 * DIMD + (size_t)(t) * 64; \
    u16* _d = Bs + (buf) * 16384 + (h) * 8192 + wv * 512; \
    GLD(_s, _d); GLD(_s + (size_t)64 * DIMD, _d + 4096); \
} while (0)

    // ds_read fragment offsets (u16 units), swizzled — measured conflict-free
    int aoff[4][2], boff[2][2];
    #pragma unroll
    for (int mf = 0; mf < 4; ++mf)
        #pragma unroll
        for (int ks = 0; ks < 2; ++ks) {
            int row = wm * 128 + mf * 16 + lr;
            aoff[mf][ks] = row * 64 + ((ks * 4 + lk) ^ (row & 7)) * 8;
        }
    #pragma unroll
    for (int nf = 0; nf < 2; ++nf)
        #pragma unroll
        for (int ks = 0; ks < 2; ++ks) {
            int row = wn * 64 + nf * 16 + lr;
            boff[nf][ks] = row * 64 + ((ks * 4 + lk) ^ (row & 7)) * 8;
        }

    f32x4 acc[8][4] = {};          // [mh*4+mf][nh*2+nf]
    bf16x8 a[4][2], b0[2][2], b1[2][2];

    // W side-channel state
    const int wcol = (bid & 7) * 512 + tid;        // n index owned by this thread
    float wreg[8];

#define READ_ALO(Ab) _Pragma("unroll") for (int mf = 0; mf < 4; ++mf) \
    _Pragma("unroll") for (int ks = 0; ks < 2; ++ks) \
        a[mf][ks] = *reinterpret_cast<const bf16x8*>((Ab) + aoff[mf][ks])
#define READ_AHI(Ab) _Pragma("unroll") for (int mf = 0; mf < 4; ++mf) \
    _Pragma("unroll") for (int ks = 0; ks < 2; ++ks) \
        a[mf][ks] = *reinterpret_cast<const bf16x8*>((Ab) + 4096 + aoff[mf][ks])
#define READ_B0(Bb) _Pragma("unroll") for (int nf = 0; nf < 2; ++nf) \
    _Pragma("unroll") for (int ks = 0; ks < 2; ++ks) \
        b0[nf][ks] = *reinterpret_cast<const bf16x8*>((Bb) + boff[nf][ks])
#define READ_B1(Bb) _Pragma("unroll") for (int nf = 0; nf < 2; ++nf) \
    _Pragma("unroll") for (int ks = 0; ks < 2; ++ks) \
        b1[nf][ks] = *reinterpret_cast<const bf16x8*>((Bb) + 2048 + boff[nf][ks])
#define MFMA_Q(MO, B, NO) _Pragma("unroll") for (int mf = 0; mf < 4; ++mf) \
    _Pragma("unroll") for (int nf = 0; nf < 2; ++nf) \
    _Pragma("unroll") for (int ks = 0; ks < 2; ++ks) \
        acc[(MO) + mf][(NO) + nf] = __builtin_amdgcn_mfma_f32_16x16x32_bf16( \
            a[mf][ks], B[nf][ks], acc[(MO) + mf][(NO) + nf], 0, 0, 0)

#define TILE(CUR, TN, PF, WEND) do { \
    const u16* Ab = As + (CUR) * 16384; \
    const u16* Bb = Bs + (CUR) * 16384; \
    READ_ALO(Ab); READ_B0(Bb); \
    LGKM8; \
    __builtin_amdgcn_s_barrier(); \
    LGKM0; \
    __builtin_amdgcn_s_setprio(1); \
    MFMA_Q(0, b0, 0); \
    __builtin_amdgcn_s_setprio(0); \
    __builtin_amdgcn_s_barrier(); \
    READ_B1(Bb); \
    __builtin_amdgcn_s_barrier(); \
    LGKM0; \
    __builtin_amdgcn_s_setprio(1); \
    MFMA_Q(0, b1, 2); \
    __builtin_amdgcn_s_setprio(0); \
    __builtin_amdgcn_s_barrier(); \
    READ_AHI(Ab); \
    if (PF) { STAGE_B(0, TN, CUR); STAGE_B(1, TN, CUR); } \
    __builtin_amdgcn_s_barrier(); \
    LGKM0; \
    __builtin_amdgcn_s_setprio(1); \
    MFMA_Q(4, b1, 2); \
    __builtin_amdgcn_s_setprio(0); \
    __builtin_amdgcn_s_barrier(); \
    if (PF) { STAGE_A(0, TN, CUR); STAGE_A(1, TN, CUR); } \
    __builtin_amdgcn_s_setprio(1); \
    MFMA_Q(4, b0, 0); \
    __builtin_amdgcn_s_setprio(0); \
    WEND; \
    __builtin_amdgcn_s_barrier(); \
} while (0)

    // prologue: tiles 0 and 1 fully issued; drain tile 0, keep tile 1 in flight
    STAGE_B(0, 0, 0); STAGE_B(1, 0, 0); STAGE_A(0, 0, 0); STAGE_A(1, 0, 0);
    STAGE_B(0, 1, 1); STAGE_B(1, 1, 1); STAGE_A(0, 1, 1); STAGE_A(1, 1, 1);
    VMW8;
    __builtin_amdgcn_s_barrier();

    for (int tt = 0; tt < NT - 2; tt += 2) {
        if (Wn) {
            if ((tt & 3) == 0) {                   // burst j = tt>>2: issue 8 loads
                int k0 = (((bid >> 3) << 4) + (tt >> 2)) << 3;
                const float* src = Wn + (size_t)k0 * DIMD + wcol;
                #pragma unroll
                for (int i = 0; i < 8; ++i) wreg[i] = src[(size_t)i * DIMD];
            } else {                               // store burst j = (tt-2)>>2
                int k0 = (((bid >> 3) << 4) + ((tt - 2) >> 2)) << 3;
                us8 o;
                #pragma unroll
                for (int i = 0; i < 8; ++i) o[i] = f2bf(wreg[i]);
                *reinterpret_cast<us8*>(WtN + (size_t)wcol * DIMD + k0) = o;
            }
        }
        TILE(0, tt + 2, true, VMW8);
        TILE(1, tt + 3, true, VMW8);
    }
    if (Wn) {                                      // final store, burst 15
        int k0 = (((bid >> 3) << 4) + 15) << 3;
        us8 o;
        #pragma unroll
        for (int i = 0; i < 8; ++i) o[i] = f2bf(wreg[i]);
        *reinterpret_cast<us8*>(WtN + (size_t)wcol * DIMD + k0) = o;
    }
    TILE(0, 0, false, VMW0);
    TILE(1, 0, false, VMW0);

    // ---- epilogue part 1: fold bias into acc; BN stats from exact fp32
    #pragma unroll
    for (int nh = 0; nh < 2; ++nh)
        #pragma unroll
        for (int nf = 0; nf < 2; ++nf) {
            int n = nh * 2 + nf;
            int col = bn * 256 + wn * 64 + n * 16 + lr;
            float bv = bias[col];
            float s1 = 0.f, s2 = 0.f;
            #pragma unroll
            for (int m = 0; m < 8; ++m)
                #pragma unroll
                for (int r = 0; r < 4; ++r) {
                    float v = acc[m][n][r] + bv;
                    acc[m][n][r] = v;
                    s1 += v; s2 += v * v;
                }
            s1 += __shfl_xor(s1, 16); s1 += __shfl_xor(s1, 32);
            s2 += __shfl_xor(s2, 16); s2 += __shfl_xor(s2, 32);
            if (lk == 0) {
                atomicAdd(&csum[col], s1);
                atomicAdd(&csum2[col], s2);
            }
        }

    // ---- epilogue part 2: per-wave LDS transpose -> 16B vector stores
    float* Ls = reinterpret_cast<float*>(As) + wv * 1088;   // 16*68 fp32/wave
    const int erow = lane >> 3, ecol = (lane & 7) * 8;
    #pragma unroll
    for (int mf = 0; mf < 8; ++mf) {
        #pragma unroll
        for (int n = 0; n < 4; ++n)
            #pragma unroll
            for (int r = 0; r < 4; ++r)
                Ls[(lk * 4 + r) * 68 + n * 16 + lr] = acc[mf][n][r];
        LGKM0;
        #pragma unroll
        for (int g = 0; g < 2; ++g) {
            int rowloc = erow + g * 8;
            size_t gidx = (size_t)(bm * 256 + wm * 128 + mf * 16 + rowloc) * DIMD
                        + bn * 256 + wn * 64 + ecol;
            const float* src = Ls + rowloc * 68 + ecol;
            if (Hf) {
                float4 v0, v1;
                v0.x = src[0]; v0.y = src[1]; v0.z = src[2]; v0.w = src[3];
                v1.x = src[4]; v1.y = src[5]; v1.z = src[6]; v1.w = src[7];
                *reinterpret_cast<float4*>(Hf + gidx) = v0;
                *reinterpret_cast<float4*>(Hf + gidx + 4) = v1;
            } else {
                us8 o;
                #pragma unroll
                for (int c = 0; c < 8; ++c) o[c] = f2bf(src[c]);
                *reinterpret_cast<us8*>(H + gidx) = o;
            }
        }
        LGKM0;   // reads retired before next mf overwrites Ls
    }
#undef TILE
#undef STAGE_A
#undef STAGE_B
}

// ------- normalize + relu -> bf16 (layers 0..2); BN finalize fused; 16B loads -------
__global__ void k_norm(const u16* __restrict__ H, const float* __restrict__ sum,
                       const float* __restrict__ sum2, const float* __restrict__ gamma,
                       const float* __restrict__ beta, u16* __restrict__ o) {
    int j = (blockIdx.x * 256 + threadIdx.x) * 8;
    int i0 = blockIdx.y * 16;
    float s[8], tt[8];
    #pragma unroll
    for (int q = 0; q < 2; ++q) {
        float4 sm = *reinterpret_cast<const float4*>(sum + j + q * 4);
        float4 s2 = *reinterpret_cast<const float4*>(sum2 + j + q * 4);
        float4 gm = *reinterpret_cast<const float4*>(gamma + j + q * 4);
        float4 bt = *reinterpret_cast<const float4*>(beta + j + q * 4);
        #pragma unroll
        for (int c = 0; c < 4; ++c) {
            float mu = (&sm.x)[c] * (1.0f / DIMB);
            float var = (&s2.x)[c] * (1.0f / DIMB) - mu * mu;
            s[q * 4 + c] = (&gm.x)[c] * rsqrtf(var + 1e-5f);
            tt[q * 4 + c] = (&bt.x)[c] - mu * s[q * 4 + c];
        }
    }
    for (int i = i0; i < i0 + 16; ++i) {
        us8 h = *reinterpret_cast<const us8*>(H + (size_t)i * DIMD + j);
        us8 r;
        #pragma unroll
        for (int c = 0; c < 8; ++c)
            r[c] = f2bf(fmaxf(bf2f(h[c]) * s[c] + tt[c], 0.0f));
        *reinterpret_cast<us8*>(o + (size_t)i * DIMD + j) = r;
    }
}

// ------- layer 3 pass A: column sums of exp(relu(norm(h))), fp32 H -------
__global__ void k_esum(const float* __restrict__ H, const float* __restrict__ sum,
                       const float* __restrict__ sum2, const float* __restrict__ gamma,
                       const float* __restrict__ beta, float* __restrict__ esum) {
    int j = (blockIdx.x * 256 + threadIdx.x) * 4;
    int i0 = blockIdx.y * 16;
    float4 sm = *reinterpret_cast<const float4*>(sum + j);
    float4 s2 = *reinterpret_cast<const float4*>(sum2 + j);
    float4 gm = *reinterpret_cast<const float4*>(gamma + j);
    float4 bt = *reinterpret_cast<const float4*>(beta + j);
    float s[4], tt[4], acc[4] = {0.f, 0.f, 0.f, 0.f};
    #pragma unroll
    for (int c = 0; c < 4; ++c) {
        float mu = (&sm.x)[c] * (1.0f / DIMB);
        float var = (&s2.x)[c] * (1.0f / DIMB) - mu * mu;
        s[c] = (&gm.x)[c] * rsqrtf(var + 1e-5f);
        tt[c] = (&bt.x)[c] - mu * s[c];
    }
    for (int i = i0; i < i0 + 16; ++i) {
        float4 h = *reinterpret_cast<const float4*>(H + (size_t)i * DIMD + j);
        #pragma unroll
        for (int c = 0; c < 4; ++c)
            acc[c] += __expf(fmaxf((&h.x)[c] * s[c] + tt[c], 0.0f));
    }
    #pragma unroll
    for (int c = 0; c < 4; ++c) atomicAdd(&esum[j + c], acc[c]);
}

// ------- layer 3 pass B: recompute exp (bit-identical), divide, in place -------
__global__ void k_final(float* __restrict__ H, const float* __restrict__ sum,
                        const float* __restrict__ sum2, const float* __restrict__ gamma,
                        const float* __restrict__ beta, const float* __restrict__ esum) {
    int j = (blockIdx.x * 256 + threadIdx.x) * 4;
    int i0 = blockIdx.y * 16;
    float4 sm = *reinterpret_cast<const float4*>(sum + j);
    float4 s2 = *reinterpret_cast<const float4*>(sum2 + j);
    float4 gm = *reinterpret_cast<const float4*>(gamma + j);
    float4 bt = *reinterpret_cast<const float4*>(beta + j);
    float4 es = *reinterpret_cast<const float4*>(esum + j);
    float s[4], tt[4], inv[4];
    #pragma unroll
    for (int c = 0; c < 4; ++c) {
        float mu = (&sm.x)[c] * (1.0f / DIMB);
        float var = (&s2.x)[c] * (1.0f / DIMB) - mu * mu;
        s[c] = (&gm.x)[c] * rsqrtf(var + 1e-5f);
        tt[c] = (&bt.x)[c] - mu * s[c];
        inv[c] = 1.0f / (&es.x)[c];
    }
    for (int i = i0; i < i0 + 16; ++i) {
        float4 h = *reinterpret_cast<const float4*>(H + (size_t)i * DIMD + j);
        float4 o;
        #pragma unroll
        for (int c = 0; c < 4; ++c)
            (&o.x)[c] = __expf(fmaxf((&h.x)[c] * s[c] + tt[c], 0.0f)) * inv[c];
        *reinterpret_cast<float4*>(H + (size_t)i * DIMD + j) = o;
    }
}

extern "C" void kernel_launch(void* const* d_in, const int* in_sizes, int n_in,
                              void* d_out, int out_size, void* d_ws, size_t ws_size,
                              hipStream_t stream) {
    (void)in_sizes; (void)n_in; (void)out_size; (void)ws_size;
    const float* x     = (const float*)d_in[0];
    const float* W     = (const float*)d_in[1];
    const float* b     = (const float*)d_in[2];
    const float* gamma = (const float*)d_in[3];
    const float* beta  = (const float*)d_in[4];
    float* out = (float*)d_out;                           // layer-3 H (fp32) + final output

    char* ws = (char*)d_ws;                               // ws = 1 GiB
    u16*  Abf = (u16*)ws;                                 // 32 MiB activation bf16
    u16*  Wt4 = (u16*)(ws + (size_t)32 * 1024 * 1024);    // 4 x 32 MiB transposed weights
    u16*  Hbf = (u16*)(ws + (size_t)160 * 1024 * 1024);   // 32 MiB hidden bf16 (layers 0-2)
    float* stats = (float*)(ws + (size_t)192 * 1024 * 1024);
    // stats: per layer l: sum = stats + l*8192, sum2 = sum + 4096; esum = stats + 32768
    hipMemsetAsync(stats, 0, (4 * 8192 + 4096) * sizeof(float), stream);

    k_cvt<<<DIMB * DIMD / 1024, 256, 0, stream>>>(x, Abf);
    k_trans<<<dim3(64, 64), 256, 0, stream>>>(W, Wt4);    // layer 0 only

    for (int l = 0; l < NLAYER; ++l) {
        float* sum = stats + l * 8192;
        float* sum2 = sum + 4096;
        float* Hf = (l == NLAYER - 1) ? out : nullptr;
        const float* Wnext = (l + 1 < NLAYER) ? W + (size_t)(l + 1) * DIMD * DIMD : nullptr;
        u16* WtNext = Wt4 + (size_t)((l + 1) & 3) * DIMD * DIMD;
        k_gemm<<<dim3(16, 16), 512, 0, stream>>>(Abf, Wt4 + (size_t)l * DIMD * DIMD,
                                                 b + l * DIMD, Hbf, Hf, sum, sum2,
                                                 Wnext, WtNext);
        if (l < NLAYER - 1)
            k_norm<<<dim3(2, 256), 256, 0, stream>>>(Hbf, sum, sum2,
                gamma + l * DIMD, beta + l * DIMD, Abf);
    }
    k_esum<<<dim3(4, 256), 256, 0, stream>>>(out, stats + 3 * 8192, stats + 3 * 8192 + 4096,
        gamma + 3 * DIMD, beta + 3 * DIMD, stats + 32768);
    k_final<<<dim3(4, 256), 256, 0, stream>>>(out, stats + 3 * 8192, stats + 3 * 8192 + 4096,
        gamma + 3 * DIMD, beta + 3 * DIMD, stats + 32768);
}

// Round 15
// 657.960 us; speedup vs baseline: 1.0098x; 1.0098x over previous
//
#include <hip/hip_runtime.h>
#include <stdint.h>

#define DIMD 4096   // feature width (and K)
#define DIMB 4096   // batch
#define NLAYER 4
#define NT (DIMD / 64)   // 64 K-tiles of BK=64

typedef unsigned short u16;
typedef __attribute__((ext_vector_type(8))) unsigned short us8;
typedef __attribute__((ext_vector_type(4))) float f32x4;
typedef __attribute__((ext_vector_type(8))) __bf16 bf16x8;

__device__ __forceinline__ u16 f2bf(float f) {
    union { float f; uint32_t u; } v; v.f = f;
    return (u16)((v.u + 0x7fffu + ((v.u >> 16) & 1u)) >> 16);  // RNE
}
__device__ __forceinline__ float bf2f(u16 u) {
    union { uint32_t u; float f; } v; v.u = ((uint32_t)u) << 16;
    return v.f;
}

// ---------------- fp32 -> bf16 elementwise (x input) ----------------
__global__ void k_cvt(const float* __restrict__ in, u16* __restrict__ out) {
    int i = (blockIdx.x * 256 + threadIdx.x) * 4;
    float4 v = *reinterpret_cast<const float4*>(in + i);
    ushort4 r;
    r.x = f2bf(v.x); r.y = f2bf(v.y); r.z = f2bf(v.z); r.w = f2bf(v.w);
    *reinterpret_cast<ushort4*>(out + i) = r;
}

// ------- W[k][n] fp32 -> Wt[n][k] bf16 (layer 0 only; layers 1-3 are
//         transposed inside the GEMMs, hidden under the K-loop) -------
__global__ void k_trans(const float* __restrict__ W, u16* __restrict__ Wt) {
    __shared__ float tile[64][65];
    const int t = threadIdx.x;
    const int n0 = blockIdx.x * 64, k0 = blockIdx.y * 64;
    const int kr = t >> 4, c4 = (t & 15) * 4;
    #pragma unroll
    for (int r = 0; r < 4; ++r) {
        float4 v = *reinterpret_cast<const float4*>(W + (size_t)(k0 + kr + r * 16) * DIMD + n0 + c4);
        tile[kr + r * 16][c4 + 0] = v.x;
        tile[kr + r * 16][c4 + 1] = v.y;
        tile[kr + r * 16][c4 + 2] = v.z;
        tile[kr + r * 16][c4 + 3] = v.w;
    }
    __syncthreads();
    const int nr = t >> 4, k4 = (t & 15) * 4;
    #pragma unroll
    for (int r = 0; r < 4; ++r) {
        int n = nr + r * 16;
        ushort4 o;
        o.x = f2bf(tile[k4 + 0][n]);
        o.y = f2bf(tile[k4 + 1][n]);
        o.z = f2bf(tile[k4 + 2][n]);
        o.w = f2bf(tile[k4 + 3][n]);
        *reinterpret_cast<ushort4*>(Wt + (size_t)(n0 + n) * DIMD + k0 + k4) = o;
    }
}

// ------- 256x256 8-phase bf16 MFMA GEMM — r3 schedule, x2 unroll -------
// + r12 LDS-transpose epilogue (16B vector C-stores)
// + r13 next-layer weight-transpose side-channel (hidden under K-loop)
// (r14's LGKM8 throttle + tail-grid bump measured neutral/negative; reverted)
#define GLD(g, l) __builtin_amdgcn_global_load_lds( \
    (__attribute__((address_space(1))) void*)(g),   \
    (__attribute__((address_space(3))) void*)(l), 16, 0, 0)

#define VMW8 asm volatile("s_waitcnt vmcnt(8)" ::: "memory")
#define VMW0 asm volatile("s_waitcnt vmcnt(0)" ::: "memory")
#define LGKM0 asm volatile("s_waitcnt lgkmcnt(0)" ::: "memory")

__global__ __launch_bounds__(512, 2) void k_gemm(
        const u16* __restrict__ A, const u16* __restrict__ Bt,
        const float* __restrict__ bias, u16* __restrict__ H,
        float* __restrict__ Hf,
        float* __restrict__ csum, float* __restrict__ csum2,
        const float* __restrict__ Wn, u16* __restrict__ WtN) {
    __shared__ __attribute__((aligned(16))) u16 As[2 * 256 * 64];   // 64 KiB
    __shared__ __attribute__((aligned(16))) u16 Bs[2 * 256 * 64];   // 64 KiB
    const int tid = threadIdx.x;
    const int lane = tid & 63, wv = tid >> 6;
    const int wm = wv >> 2, wn = wv & 3;          // 2 x 4 wave grid
    const int bm = blockIdx.y, bn = blockIdx.x;
    const int bid = bm * 16 + bn;                 // 0..255 for W side-channel
    const int lr = lane & 15, lk = lane >> 4;

    // staging geometry: per GLD issue, 512 threads x 16B cover 64 rows x 64 cols
    const int r0 = tid >> 3;                       // 0..63
    const int cswz = (tid & 7) ^ (r0 & 7);         // inverse-swizzled 16B chunk
    const u16* gA = A  + (size_t)(bm * 256 + r0) * DIMD + cswz * 8;
    const u16* gB = Bt + (size_t)(bn * 256 + r0) * DIMD + cswz * 8;

#define STAGE_A(h, t, buf) do { \
    const u16* _s = gA + (size_t)(h) * 128 * DIMD + (size_t)(t) * 64; \
    u16* _d = As + (buf) * 16384 + (h) * 8192 + wv * 512; \
    GLD(_s, _d); GLD(_s + (size_t)64 * DIMD, _d + 4096); \
} while (0)
#define STAGE_B(h, t, buf) do { \
    const u16* _s = gB + (size_t)(h) * 128 * DIMD + (size_t)(t) * 64; \
    u16* _d = Bs + (buf) * 16384 + (h) * 8192 + wv * 512; \
    GLD(_s, _d); GLD(_s + (size_t)64 * DIMD, _d + 4096); \
} while (0)

    // ds_read fragment offsets (u16 units), swizzled — measured conflict-free
    int aoff[4][2], boff[2][2];
    #pragma unroll
    for (int mf = 0; mf < 4; ++mf)
        #pragma unroll
        for (int ks = 0; ks < 2; ++ks) {
            int row = wm * 128 + mf * 16 + lr;
            aoff[mf][ks] = row * 64 + ((ks * 4 + lk) ^ (row & 7)) * 8;
        }
    #pragma unroll
    for (int nf = 0; nf < 2; ++nf)
        #pragma unroll
        for (int ks = 0; ks < 2; ++ks) {
            int row = wn * 64 + nf * 16 + lr;
            boff[nf][ks] = row * 64 + ((ks * 4 + lk) ^ (row & 7)) * 8;
        }

    f32x4 acc[8][4] = {};          // [mh*4+mf][nh*2+nf]
    bf16x8 a[4][2], b0[2][2], b1[2][2];

    // W side-channel state
    const int wcol = (bid & 7) * 512 + tid;        // n index owned by this thread
    float wreg[8];

#define READ_ALO(Ab) _Pragma("unroll") for (int mf = 0; mf < 4; ++mf) \
    _Pragma("unroll") for (int ks = 0; ks < 2; ++ks) \
        a[mf][ks] = *reinterpret_cast<const bf16x8*>((Ab) + aoff[mf][ks])
#define READ_AHI(Ab) _Pragma("unroll") for (int mf = 0; mf < 4; ++mf) \
    _Pragma("unroll") for (int ks = 0; ks < 2; ++ks) \
        a[mf][ks] = *reinterpret_cast<const bf16x8*>((Ab) + 4096 + aoff[mf][ks])
#define READ_B0(Bb) _Pragma("unroll") for (int nf = 0; nf < 2; ++nf) \
    _Pragma("unroll") for (int ks = 0; ks < 2; ++ks) \
        b0[nf][ks] = *reinterpret_cast<const bf16x8*>((Bb) + boff[nf][ks])
#define READ_B1(Bb) _Pragma("unroll") for (int nf = 0; nf < 2; ++nf) \
    _Pragma("unroll") for (int ks = 0; ks < 2; ++ks) \
        b1[nf][ks] = *reinterpret_cast<const bf16x8*>((Bb) + 2048 + boff[nf][ks])
#define MFMA_Q(MO, B, NO) _Pragma("unroll") for (int mf = 0; mf < 4; ++mf) \
    _Pragma("unroll") for (int nf = 0; nf < 2; ++nf) \
    _Pragma("unroll") for (int ks = 0; ks < 2; ++ks) \
        acc[(MO) + mf][(NO) + nf] = __builtin_amdgcn_mfma_f32_16x16x32_bf16( \
            a[mf][ks], B[nf][ks], acc[(MO) + mf][(NO) + nf], 0, 0, 0)

#define TILE(CUR, TN, PF, WEND) do { \
    const u16* Ab = As + (CUR) * 16384; \
    const u16* Bb = Bs + (CUR) * 16384; \
    READ_ALO(Ab); READ_B0(Bb); \
    __builtin_amdgcn_s_barrier(); \
    LGKM0; \
    __builtin_amdgcn_s_setprio(1); \
    MFMA_Q(0, b0, 0); \
    __builtin_amdgcn_s_setprio(0); \
    __builtin_amdgcn_s_barrier(); \
    READ_B1(Bb); \
    __builtin_amdgcn_s_barrier(); \
    LGKM0; \
    __builtin_amdgcn_s_setprio(1); \
    MFMA_Q(0, b1, 2); \
    __builtin_amdgcn_s_setprio(0); \
    __builtin_amdgcn_s_barrier(); \
    READ_AHI(Ab); \
    if (PF) { STAGE_B(0, TN, CUR); STAGE_B(1, TN, CUR); } \
    __builtin_amdgcn_s_barrier(); \
    LGKM0; \
    __builtin_amdgcn_s_setprio(1); \
    MFMA_Q(4, b1, 2); \
    __builtin_amdgcn_s_setprio(0); \
    __builtin_amdgcn_s_barrier(); \
    if (PF) { STAGE_A(0, TN, CUR); STAGE_A(1, TN, CUR); } \
    __builtin_amdgcn_s_setprio(1); \
    MFMA_Q(4, b0, 0); \
    __builtin_amdgcn_s_setprio(0); \
    WEND; \
    __builtin_amdgcn_s_barrier(); \
} while (0)

    // prologue: tiles 0 and 1 fully issued; drain tile 0, keep tile 1 in flight
    STAGE_B(0, 0, 0); STAGE_B(1, 0, 0); STAGE_A(0, 0, 0); STAGE_A(1, 0, 0);
    STAGE_B(0, 1, 1); STAGE_B(1, 1, 1); STAGE_A(0, 1, 1); STAGE_A(1, 1, 1);
    VMW8;
    __builtin_amdgcn_s_barrier();

    for (int tt = 0; tt < NT - 2; tt += 2) {
        if (Wn) {
            if ((tt & 3) == 0) {                   // burst j = tt>>2: issue 8 loads
                int k0 = (((bid >> 3) << 4) + (tt >> 2)) << 3;
                const float* src = Wn + (size_t)k0 * DIMD + wcol;
                #pragma unroll
                for (int i = 0; i < 8; ++i) wreg[i] = src[(size_t)i * DIMD];
            } else {                               // store burst j = (tt-2)>>2
                int k0 = (((bid >> 3) << 4) + ((tt - 2) >> 2)) << 3;
                us8 o;
                #pragma unroll
                for (int i = 0; i < 8; ++i) o[i] = f2bf(wreg[i]);
                *reinterpret_cast<us8*>(WtN + (size_t)wcol * DIMD + k0) = o;
            }
        }
        TILE(0, tt + 2, true, VMW8);
        TILE(1, tt + 3, true, VMW8);
    }
    if (Wn) {                                      // final store, burst 15
        int k0 = (((bid >> 3) << 4) + 15) << 3;
        us8 o;
        #pragma unroll
        for (int i = 0; i < 8; ++i) o[i] = f2bf(wreg[i]);
        *reinterpret_cast<us8*>(WtN + (size_t)wcol * DIMD + k0) = o;
    }
    TILE(0, 0, false, VMW0);
    TILE(1, 0, false, VMW0);

    // ---- epilogue part 1: fold bias into acc; BN stats from exact fp32
    #pragma unroll
    for (int nh = 0; nh < 2; ++nh)
        #pragma unroll
        for (int nf = 0; nf < 2; ++nf) {
            int n = nh * 2 + nf;
            int col = bn * 256 + wn * 64 + n * 16 + lr;
            float bv = bias[col];
            float s1 = 0.f, s2 = 0.f;
            #pragma unroll
            for (int m = 0; m < 8; ++m)
                #pragma unroll
                for (int r = 0; r < 4; ++r) {
                    float v = acc[m][n][r] + bv;
                    acc[m][n][r] = v;
                    s1 += v; s2 += v * v;
                }
            s1 += __shfl_xor(s1, 16); s1 += __shfl_xor(s1, 32);
            s2 += __shfl_xor(s2, 16); s2 += __shfl_xor(s2, 32);
            if (lk == 0) {
                atomicAdd(&csum[col], s1);
                atomicAdd(&csum2[col], s2);
            }
        }

    // ---- epilogue part 2: per-wave LDS transpose -> 16B vector stores
    float* Ls = reinterpret_cast<float*>(As) + wv * 1088;   // 16*68 fp32/wave
    const int erow = lane >> 3, ecol = (lane & 7) * 8;
    #pragma unroll
    for (int mf = 0; mf < 8; ++mf) {
        #pragma unroll
        for (int n = 0; n < 4; ++n)
            #pragma unroll
            for (int r = 0; r < 4; ++r)
                Ls[(lk * 4 + r) * 68 + n * 16 + lr] = acc[mf][n][r];
        LGKM0;
        #pragma unroll
        for (int g = 0; g < 2; ++g) {
            int rowloc = erow + g * 8;
            size_t gidx = (size_t)(bm * 256 + wm * 128 + mf * 16 + rowloc) * DIMD
                        + bn * 256 + wn * 64 + ecol;
            const float* src = Ls + rowloc * 68 + ecol;
            if (Hf) {
                float4 v0, v1;
                v0.x = src[0]; v0.y = src[1]; v0.z = src[2]; v0.w = src[3];
                v1.x = src[4]; v1.y = src[5]; v1.z = src[6]; v1.w = src[7];
                *reinterpret_cast<float4*>(Hf + gidx) = v0;
                *reinterpret_cast<float4*>(Hf + gidx + 4) = v1;
            } else {
                us8 o;
                #pragma unroll
                for (int c = 0; c < 8; ++c) o[c] = f2bf(src[c]);
                *reinterpret_cast<us8*>(H + gidx) = o;
            }
        }
        LGKM0;   // reads retired before next mf overwrites Ls
    }
#undef TILE
#undef STAGE_A
#undef STAGE_B
}

// ------- normalize + relu -> bf16 (layers 0..2); BN finalize fused; 16B loads -------
__global__ void k_norm(const u16* __restrict__ H, const float* __restrict__ sum,
                       const float* __restrict__ sum2, const float* __restrict__ gamma,
                       const float* __restrict__ beta, u16* __restrict__ o) {
    int j = (blockIdx.x * 256 + threadIdx.x) * 8;
    int i0 = blockIdx.y * 32;
    float s[8], tt[8];
    #pragma unroll
    for (int q = 0; q < 2; ++q) {
        float4 sm = *reinterpret_cast<const float4*>(sum + j + q * 4);
        float4 s2 = *reinterpret_cast<const float4*>(sum2 + j + q * 4);
        float4 gm = *reinterpret_cast<const float4*>(gamma + j + q * 4);
        float4 bt = *reinterpret_cast<const float4*>(beta + j + q * 4);
        #pragma unroll
        for (int c = 0; c < 4; ++c) {
            float mu = (&sm.x)[c] * (1.0f / DIMB);
            float var = (&s2.x)[c] * (1.0f / DIMB) - mu * mu;
            s[q * 4 + c] = (&gm.x)[c] * rsqrtf(var + 1e-5f);
            tt[q * 4 + c] = (&bt.x)[c] - mu * s[q * 4 + c];
        }
    }
    for (int i = i0; i < i0 + 32; ++i) {
        us8 h = *reinterpret_cast<const us8*>(H + (size_t)i * DIMD + j);
        us8 r;
        #pragma unroll
        for (int c = 0; c < 8; ++c)
            r[c] = f2bf(fmaxf(bf2f(h[c]) * s[c] + tt[c], 0.0f));
        *reinterpret_cast<us8*>(o + (size_t)i * DIMD + j) = r;
    }
}

// ------- layer 3 pass A: column sums of exp(relu(norm(h))), fp32 H -------
__global__ void k_esum(const float* __restrict__ H, const float* __restrict__ sum,
                       const float* __restrict__ sum2, const float* __restrict__ gamma,
                       const float* __restrict__ beta, float* __restrict__ esum) {
    int j = (blockIdx.x * 256 + threadIdx.x) * 4;
    int i0 = blockIdx.y * 32;
    float4 sm = *reinterpret_cast<const float4*>(sum + j);
    float4 s2 = *reinterpret_cast<const float4*>(sum2 + j);
    float4 gm = *reinterpret_cast<const float4*>(gamma + j);
    float4 bt = *reinterpret_cast<const float4*>(beta + j);
    float s[4], tt[4], acc[4] = {0.f, 0.f, 0.f, 0.f};
    #pragma unroll
    for (int c = 0; c < 4; ++c) {
        float mu = (&sm.x)[c] * (1.0f / DIMB);
        float var = (&s2.x)[c] * (1.0f / DIMB) - mu * mu;
        s[c] = (&gm.x)[c] * rsqrtf(var + 1e-5f);
        tt[c] = (&bt.x)[c] - mu * s[c];
    }
    for (int i = i0; i < i0 + 32; ++i) {
        float4 h = *reinterpret_cast<const float4*>(H + (size_t)i * DIMD + j);
        #pragma unroll
        for (int c = 0; c < 4; ++c)
            acc[c] += __expf(fmaxf((&h.x)[c] * s[c] + tt[c], 0.0f));
    }
    #pragma unroll
    for (int c = 0; c < 4; ++c) atomicAdd(&esum[j + c], acc[c]);
}

// ------- layer 3 pass B: recompute exp (bit-identical), divide, in place -------
__global__ void k_final(float* __restrict__ H, const float* __restrict__ sum,
                        const float* __restrict__ sum2, const float* __restrict__ gamma,
                        const float* __restrict__ beta, const float* __restrict__ esum) {
    int j = (blockIdx.x * 256 + threadIdx.x) * 4;
    int i0 = blockIdx.y * 32;
    float4 sm = *reinterpret_cast<const float4*>(sum + j);
    float4 s2 = *reinterpret_cast<const float4*>(sum2 + j);
    float4 gm = *reinterpret_cast<const float4*>(gamma + j);
    float4 bt = *reinterpret_cast<const float4*>(beta + j);
    float4 es = *reinterpret_cast<const float4*>(esum + j);
    float s[4], tt[4], inv[4];
    #pragma unroll
    for (int c = 0; c < 4; ++c) {
        float mu = (&sm.x)[c] * (1.0f / DIMB);
        float var = (&s2.x)[c] * (1.0f / DIMB) - mu * mu;
        s[c] = (&gm.x)[c] * rsqrtf(var + 1e-5f);
        tt[c] = (&bt.x)[c] - mu * s[c];
        inv[c] = 1.0f / (&es.x)[c];
    }
    for (int i = i0; i < i0 + 32; ++i) {
        float4 h = *reinterpret_cast<const float4*>(H + (size_t)i * DIMD + j);
        float4 o;
        #pragma unroll
        for (int c = 0; c < 4; ++c)
            (&o.x)[c] = __expf(fmaxf((&h.x)[c] * s[c] + tt[c], 0.0f)) * inv[c];
        *reinterpret_cast<float4*>(H + (size_t)i * DIMD + j) = o;
    }
}

extern "C" void kernel_launch(void* const* d_in, const int* in_sizes, int n_in,
                              void* d_out, int out_size, void* d_ws, size_t ws_size,
                              hipStream_t stream) {
    (void)in_sizes; (void)n_in; (void)out_size; (void)ws_size;
    const float* x     = (const float*)d_in[0];
    const float* W     = (const float*)d_in[1];
    const float* b     = (const float*)d_in[2];
    const float* gamma = (const float*)d_in[3];
    const float* beta  = (const float*)d_in[4];
    float* out = (float*)d_out;                           // layer-3 H (fp32) + final output

    char* ws = (char*)d_ws;                               // ws = 1 GiB
    u16*  Abf = (u16*)ws;                                 // 32 MiB activation bf16
    u16*  Wt4 = (u16*)(ws + (size_t)32 * 1024 * 1024);    // 4 x 32 MiB transposed weights
    u16*  Hbf = (u16*)(ws + (size_t)160 * 1024 * 1024);   // 32 MiB hidden bf16 (layers 0-2)
    float* stats = (float*)(ws + (size_t)192 * 1024 * 1024);
    // stats: per layer l: sum = stats + l*8192, sum2 = sum + 4096; esum = stats + 32768
    hipMemsetAsync(stats, 0, (4 * 8192 + 4096) * sizeof(float), stream);

    k_cvt<<<DIMB * DIMD / 1024, 256, 0, stream>>>(x, Abf);
    k_trans<<<dim3(64, 64), 256, 0, stream>>>(W, Wt4);    // layer 0 only

    for (int l = 0; l < NLAYER; ++l) {
        float* sum = stats + l * 8192;
        float* sum2 = sum + 4096;
        float* Hf = (l == NLAYER - 1) ? out : nullptr;
        const float* Wnext = (l + 1 < NLAYER) ? W + (size_t)(l + 1) * DIMD * DIMD : nullptr;
        u16* WtNext = Wt4 + (size_t)((l + 1) & 3) * DIMD * DIMD;
        k_gemm<<<dim3(16, 16), 512, 0, stream>>>(Abf, Wt4 + (size_t)l * DIMD * DIMD,
                                                 b + l * DIMD, Hbf, Hf, sum, sum2,
                                                 Wnext, WtNext);
        if (l < NLAYER - 1)
            k_norm<<<dim3(2, 128), 256, 0, stream>>>(Hbf, sum, sum2,
                gamma + l * DIMD, beta + l * DIMD, Abf);
    }
    k_esum<<<dim3(4, 128), 256, 0, stream>>>(out, stats + 3 * 8192, stats + 3 * 8192 + 4096,
        gamma + 3 * DIMD, beta + 3 * DIMD, stats + 32768);
    k_final<<<dim3(4, 128), 256, 0, stream>>>(out, stats + 3 * 8192, stats + 3 * 8192 + 4096,
        gamma + 3 * DIMD, beta + 3 * DIMD, stats + 32768);
}